// Round 7
// baseline (13638.539 us; speedup 1.0000x reference)
//
#include <hip/hip_runtime.h>
#include <hip/hip_bf16.h>

typedef __attribute__((ext_vector_type(8))) short bf16x8;
typedef __attribute__((ext_vector_type(4))) float f32x4;

#define HD   768
#define NB   64
#define NT   256
#define NGATE 3072   // 4*HD
#define FPAD 32      // flag padding: 32 ints = 128 B (one cache line)

__device__ __forceinline__ float fast_sig(float x) { return 1.f / (1.f + __expf(-x)); }
__device__ __forceinline__ float fast_tanh(float x) {
  float t = __expf(-2.f * fabsf(x));
  float r = (1.f - t) / (1.f + t);
  return x < 0.f ? -r : r;
}
__device__ __forceinline__ float bf2f(unsigned short u) {
  union { unsigned i; float f; } v; v.i = ((unsigned)u) << 16; return v.f;
}
__device__ __forceinline__ unsigned short f2bfu(float f) {
  union { __hip_bfloat16 b; unsigned short u; } c;
  c.b = __float2bfloat16(f);
  return c.u;
}
__device__ __forceinline__ unsigned pack2(float a, float b) {
  return (unsigned)f2bfu(a) | ((unsigned)f2bfu(b) << 16);
}

// ---------------------------------------------------------------------------
// Coherent-path primitives: relaxed agent atomics (sc0 sc1 -> LLC, bypassing
// the non-cross-coherent per-XCD L2). NO buffer_wbl2 / buffer_inv anywhere.
// ---------------------------------------------------------------------------
__device__ __forceinline__ int aload(int* p) {
  return __hip_atomic_load(p, __ATOMIC_RELAXED, __HIP_MEMORY_SCOPE_AGENT);
}
__device__ __forceinline__ unsigned uload(const unsigned* p) {
  return __hip_atomic_load((unsigned*)p, __ATOMIC_RELAXED, __HIP_MEMORY_SCOPE_AGENT);
}
__device__ __forceinline__ void ustore(unsigned* p, unsigned v) {
  __hip_atomic_store(p, v, __ATOMIC_RELAXED, __HIP_MEMORY_SCOPE_AGENT);
}

// Publish: drain this thread's (coherent) stores, block barrier, flag RMW.
__device__ __forceinline__ void arrive_flag(int* f) {
  asm volatile("s_waitcnt vmcnt(0)" ::: "memory");   // sc1 stores are at LLC
  __syncthreads();
  if (threadIdx.x == 0)
    __hip_atomic_fetch_add(f, 1, __ATOMIC_RELAXED, __HIP_MEMORY_SCOPE_AGENT);
}

// Wait until all 96 flags in fa >= ta AND (fb: all 96 flags in fb >= tb).
// Threads 0..95 poll fa, 128..223 poll fb. Bounded spin -> fast-fail.
// No acquire fence needed: all mutable-data reads go through uload (LLC).
__device__ __forceinline__ void wait2(int* fa, int ta, int* fb, int tb) {
  int tid = threadIdx.x;
  int* p = nullptr; int tgt = 0;
  if (tid < 96)                            { p = fa + tid * FPAD;         tgt = ta; }
  else if (fb && tid >= 128 && tid < 224)  { p = fb + (tid - 128) * FPAD; tgt = tb; }
  if (p && tgt > 0) {
    int guard = 0;
    while (aload(p) < tgt) {
      __builtin_amdgcn_s_sleep(1);
      if (++guard > (1 << 17)) break;      // deadlock -> wrong answer fast, not hang
    }
  }
  __syncthreads();                         // all flags observed; also compiler fence
}

// ---------------------------------------------------------------------------
// Load a 32-row weight slice into LDS, XOR-swizzled:
//   lds_byte(r, cb) = r*K*2 + (cb ^ ((r&7)<<4))
// ---------------------------------------------------------------------------
__device__ __forceinline__ void load_W_lds(unsigned short* Wl,
                                           const __hip_bfloat16* Wg,
                                           int n_base, int K)
{
  int chunksPerRow = (K * 2) / 16;
  int total = 32 * chunksPerRow;
  for (int idx = threadIdx.x; idx < total; idx += 256) {
    int r  = idx / chunksPerRow;
    int cb = (idx % chunksPerRow) * 16;
    bf16x8 v = *(const bf16x8*)((const char*)(Wg + (long)(n_base + r) * K) + cb);
    *(bf16x8*)((char*)Wl + (long)r * (K * 2) + (cb ^ ((r & 7) << 4))) = v;
  }
}

// ---------------------------------------------------------------------------
// Per-step GEMM, B from swizzled LDS. A comes from three k-ranges:
//   it in [0,C0):   cached bf16x8 loads from A0 (read-only data)
//   it in [C0,C1):  coherent dword loads from U1 (cross-block, stride s1 dw)
//   it in [C1,NIT): coherent dword loads from U2 (cross-block, stride s2 dw)
// Result (64x32 gate tile) left in gl.
// ---------------------------------------------------------------------------
template<int C0, int C1, int NIT>
__device__ __forceinline__ void mfma_gates_t(
    const unsigned short* Wl, const int Kbytes,
    const __hip_bfloat16* __restrict__ A0, long strideA0,
    const unsigned* __restrict__ U1, int s1,
    const unsigned* __restrict__ U2, int s2,
    float (*gl)[33])
{
  int tid = threadIdx.x;
  int w = tid >> 6, l = tid & 63, lr = l & 15, lh = l >> 4;
  f32x4 acc0 = {0.f, 0.f, 0.f, 0.f};
  f32x4 acc1 = {0.f, 0.f, 0.f, 0.f};
  int bA = 16 * w + lr;
  const __hip_bfloat16* a0p = (C0 > 0) ? (A0 + (long)bA * strideA0) : nullptr;
  const unsigned* u1p = (C1 > C0) ? (U1 + bA * s1 + 4 * lh) : nullptr;
  const unsigned* u2p = (NIT > C1) ? (U2 + bA * s2 + 4 * lh) : nullptr;
  const char* w0 = (const char*)Wl + lr * Kbytes;
  const char* w1 = (const char*)Wl + (16 + lr) * Kbytes;
  int xr = (lr & 7) << 4;
  int kk = 8 * lh;

  #pragma unroll 4
  for (int it = 0; it < C0; ++it) {
    bf16x8 av = *(const bf16x8*)(a0p + it * 32 + kk);
    int o = ((it * 32 + kk) * 2) ^ xr;
    bf16x8 bv0 = *(const bf16x8*)(w0 + o);
    bf16x8 bv1 = *(const bf16x8*)(w1 + o);
    acc0 = __builtin_amdgcn_mfma_f32_16x16x32_bf16(av, bv0, acc0, 0, 0, 0);
    acc1 = __builtin_amdgcn_mfma_f32_16x16x32_bf16(av, bv1, acc1, 0, 0, 0);
  }
  #pragma unroll 4
  for (int it = C0; it < C1; ++it) {
    const unsigned* p = u1p + (it - C0) * 16;
    union { unsigned u[4]; bf16x8 v; } cv;
    cv.u[0] = uload(p + 0); cv.u[1] = uload(p + 1);
    cv.u[2] = uload(p + 2); cv.u[3] = uload(p + 3);
    int o = ((it * 32 + kk) * 2) ^ xr;
    bf16x8 bv0 = *(const bf16x8*)(w0 + o);
    bf16x8 bv1 = *(const bf16x8*)(w1 + o);
    acc0 = __builtin_amdgcn_mfma_f32_16x16x32_bf16(cv.v, bv0, acc0, 0, 0, 0);
    acc1 = __builtin_amdgcn_mfma_f32_16x16x32_bf16(cv.v, bv1, acc1, 0, 0, 0);
  }
  #pragma unroll 4
  for (int it = C1; it < NIT; ++it) {
    const unsigned* p = u2p + (it - C1) * 16;
    union { unsigned u[4]; bf16x8 v; } cv;
    cv.u[0] = uload(p + 0); cv.u[1] = uload(p + 1);
    cv.u[2] = uload(p + 2); cv.u[3] = uload(p + 3);
    int o = ((it * 32 + kk) * 2) ^ xr;
    bf16x8 bv0 = *(const bf16x8*)(w0 + o);
    bf16x8 bv1 = *(const bf16x8*)(w1 + o);
    acc0 = __builtin_amdgcn_mfma_f32_16x16x32_bf16(cv.v, bv0, acc0, 0, 0, 0);
    acc1 = __builtin_amdgcn_mfma_f32_16x16x32_bf16(cv.v, bv1, acc1, 0, 0, 0);
  }
  #pragma unroll
  for (int r = 0; r < 4; ++r) {
    gl[16 * w + 4 * lh + r][lr]      = acc0[r];
    gl[16 * w + 4 * lh + r][16 + lr] = acc1[r];
  }
}

// ---------------------------------------------------------------------------
// Setup kernels
// ---------------------------------------------------------------------------
__global__ void cvt_bf16_kernel(const float* __restrict__ src,
                                __hip_bfloat16* __restrict__ dst, long n)
{
  long i = (long)blockIdx.x * blockDim.x + threadIdx.x;
  long stride = (long)gridDim.x * blockDim.x;
  for (; i < n; i += stride) dst[i] = __float2bfloat16(src[i]);
}

// dst[n'][k], n' = j*4 + g; k < Kih -> Wih, else Whh
__global__ void pack_w_kernel(const float* __restrict__ Wih,
                              const float* __restrict__ Whh,
                              __hip_bfloat16* __restrict__ dst, int Kih)
{
  int K = Kih + HD;
  long total = (long)NGATE * K;
  long stride = (long)gridDim.x * blockDim.x;
  for (long idx = (long)blockIdx.x * blockDim.x + threadIdx.x; idx < total; idx += stride) {
    int np = (int)(idx / K), k = (int)(idx % K);
    int j = np >> 2, g = np & 3;
    int n = g * HD + j;
    float v = (k < Kih) ? Wih[(long)n * Kih + k] : Whh[(long)n * HD + (k - Kih)];
    dst[idx] = __float2bfloat16(v);
  }
}

__global__ void fill_sentinel(float* out, int n, float v)
{
  int i = blockIdx.x * blockDim.x + threadIdx.x;
  if (i < n) out[i] = v;
}

// ---------------------------------------------------------------------------
// Phase 1 persistent: BiLSTM, 192 blocks (0-95 fwd, 96-191 bwd), 256 steps.
// W-slice in LDS; c-state in registers; h exchanged through LLC (packed
// dword atomics), double-buffered; per-direction flag barrier per step.
// ---------------------------------------------------------------------------
__global__ __launch_bounds__(256, 1) void bilstm_persist(
    const __hip_bfloat16* __restrict__ X16,   // [64][256][768]
    const __hip_bfloat16* __restrict__ WF,
    const __hip_bfloat16* __restrict__ WB,
    const float* __restrict__ bF, const float* __restrict__ bB,
    unsigned* __restrict__ H16u,              // [2 par][2 dir][64][384] dw
    __hip_bfloat16* __restrict__ L16,         // [64][256][1536]
    int* __restrict__ flags)                  // [2 dir][96*FPAD]
{
  __shared__ unsigned short Wl[32 * 1536];    // 96 KiB
  __shared__ float gl[64][33];
  int blk = blockIdx.x, dir = blk / 96, nt = blk % 96;
  load_W_lds(Wl, dir ? WB : WF, nt * 32, 1536);
  const float* bias = dir ? bB : bF;
  int* myflags = flags + dir * 96 * FPAD;
  int tid = threadIdx.x;
  unsigned* L16u = (unsigned*)L16;

  int e0 = tid * 2;
  int b = e0 >> 3, jj = e0 & 7;        // jj even; both elems share row b
  int j0 = nt * 8 + jj;
  float bv[2][4];
  #pragma unroll
  for (int u = 0; u < 2; ++u) {
    bv[u][0] = bias[j0 + u];          bv[u][1] = bias[HD + j0 + u];
    bv[u][2] = bias[2 * HD + j0 + u]; bv[u][3] = bias[3 * HD + j0 + u];
  }
  float cst[2] = {0.f, 0.f};
  __syncthreads();

  for (int s = 0; s < NT; ++s) {
    int par = s & 1;
    int t = dir ? (NT - 1 - s) : s;
    if (s > 0) wait2(myflags, s, nullptr, 0);   // all blocks finished step s-1
    mfma_gates_t<24, 48, 48>(Wl, 3072,
                             X16 + (long)t * HD, (long)NT * HD,
                             H16u + (long)(par * 2 + dir) * (NB * 384), 384,
                             nullptr, 0, gl);
    __syncthreads();
    float hv[2];
    #pragma unroll
    for (int u = 0; u < 2; ++u) {
      int col = 4 * (jj + u);
      float vi = gl[b][col + 0] + bv[u][0];
      float vf = gl[b][col + 1] + bv[u][1];
      float vg = gl[b][col + 2] + bv[u][2];
      float vo = gl[b][col + 3] + bv[u][3];
      float si = fast_sig(vi), sf = fast_sig(vf), so = fast_sig(vo);
      float tg = fast_tanh(vg);
      float c = sf * cst[u] + si * tg;
      cst[u] = c;
      hv[u] = so * fast_tanh(c);
    }
    unsigned pk = pack2(hv[0], hv[1]);
    ustore(H16u + (long)((par ^ 1) * 2 + dir) * (NB * 384) + b * 384 + (j0 >> 1), pk);
    L16u[((long)b * NT + t) * 768 + dir * 384 + (j0 >> 1)] = pk;   // cached store OK (read next kernel)
    if (s < NT - 1) arrive_flag(myflags + nt * FPAD);
  }
}

// ---------------------------------------------------------------------------
// cls x-part (vectorized) + pred0
// ---------------------------------------------------------------------------
__global__ __launch_bounds__(256) void clsx_kernel(
    const __hip_bfloat16* __restrict__ L16,
    const float* __restrict__ clsW, const float* __restrict__ clsb,
    float* __restrict__ out)
{
  int t = blockIdx.x;
  int tid = threadIdx.x;
  if (tid >= 128) return;
  int b = tid >> 1, o = tid & 1;
  if (t == 0) {
    out[((long)b * NT) * 2 + o] = o ? 1.f : -1.f;
    return;
  }
  const bf16x8* xp = (const bf16x8*)(L16 + ((long)b * NT + t) * 1536);
  const float* w = clsW + o * 2304 + HD;
  float s = clsb[o];
  for (int k = 0; k < 192; ++k) {
    bf16x8 v = xp[k];
    #pragma unroll
    for (int e = 0; e < 8; ++e)
      s += bf2f((unsigned short)v[e]) * w[k * 8 + e];
  }
  out[((long)b * NT + t) * 2 + o] = s;
}

// ---------------------------------------------------------------------------
// Phase 2 persistent: 192 blocks (0-95 subword chain, 96-191 word chain),
// producer-consumer via 4-deep SUBW ring + flag arrays.
//   subword step s: needs flagS>=s (h1 exchange), flagW>=s-3 (ring free)
//   word    step s: needs flagS>=s+1 (SUBW[s] ready), flagW>=s (h2 exchange)
// All cross-block data (H1S, H2S, SUBW) through LLC coherent dword atomics.
// ---------------------------------------------------------------------------
__global__ __launch_bounds__(256, 1) void stack_persist(
    const __hip_bfloat16* __restrict__ L16,
    const __hip_bfloat16* __restrict__ WS,
    const __hip_bfloat16* __restrict__ WW,
    const float* __restrict__ bS, const float* __restrict__ bW,
    const int* __restrict__ golds,
    const float* __restrict__ clsW,
    unsigned* __restrict__ H1Su,   // [2][64][384] dw
    unsigned* __restrict__ H2Su,   // [2][64][384] dw
    unsigned* __restrict__ SUBWu,  // [4][64][768] dw ring ([h1|c1] per row)
    float* __restrict__ out,
    int* __restrict__ flags)       // [+2*96*FPAD: S] [+3*96*FPAD: W]
{
  __shared__ unsigned short Wl[32 * 2304];  // 144 KiB
  __shared__ float gl[64][33];
  int blk = blockIdx.x, role = blk / 96, nt = blk % 96;
  int* flagS = flags + 2 * 96 * FPAD;
  int* flagW = flags + 3 * 96 * FPAD;
  const float* bias = role ? bW : bS;
  load_W_lds(Wl, role ? WW : WS, nt * 32, 2304);
  int tid = threadIdx.x;

  int e0 = tid * 2;
  int b = e0 >> 3, jj = e0 & 7;        // jj even
  int j0 = nt * 8 + jj;
  float bv[2][4];
  #pragma unroll
  for (int u = 0; u < 2; ++u) {
    bv[u][0] = bias[j0 + u];          bv[u][1] = bias[HD + j0 + u];
    bv[u][2] = bias[2 * HD + j0 + u]; bv[u][3] = bias[3 * HD + j0 + u];
  }
  const int* gp = golds + b * NT + 1;   // gp[s] = golds[b][s+1]
  float cst[2] = {0.f, 0.f};
  float hreg[2] = {0.f, 0.f};
  __syncthreads();

  if (role == 0) {
    // ---- subword chain ----
    for (int s = 0; s < NT - 1; ++s) {
      wait2(flagS, s, flagW, s - 3);
      mfma_gates_t<48, 72, 72>(Wl, 4608,
                               L16 + (long)s * 1536, (long)NT * 1536,
                               H1Su + (long)(s & 1) * (NB * 384), 384,
                               nullptr, 0, gl);
      __syncthreads();
      float h1v[2], c1v[2];
      #pragma unroll
      for (int u = 0; u < 2; ++u) {
        int col = 4 * (jj + u);
        float vi = gl[b][col + 0] + bv[u][0];
        float vf = gl[b][col + 1] + bv[u][1];
        float vg = gl[b][col + 2] + bv[u][2];
        float vo = gl[b][col + 3] + bv[u][3];
        float si = fast_sig(vi), sf = fast_sig(vf), so = fast_sig(vo);
        float tg = fast_tanh(vg);
        c1v[u] = sf * cst[u] + si * tg;
        h1v[u] = so * fast_tanh(c1v[u]);
      }
      int g = gp[s];
      bool push = (g == 0);
      unsigned pkh = pack2(h1v[0], h1v[1]);
      unsigned pkc = pack2(c1v[0], c1v[1]);
      unsigned* sb = SUBWu + (long)(s & 3) * (NB * 768) + b * 768;
      ustore(sb + (j0 >> 1), pkh);
      ustore(sb + 384 + (j0 >> 1), pkc);
      ustore(H1Su + (long)((s + 1) & 1) * (NB * 384) + b * 384 + (j0 >> 1),
             push ? pkh : 0u);
      cst[0] = push ? c1v[0] : 0.f;
      cst[1] = push ? c1v[1] : 0.f;
      arrive_flag(flagS + nt * FPAD);
    }
  } else {
    // ---- word chain ----
    float cw0[2], cw1[2];
    #pragma unroll
    for (int u = 0; u < 2; ++u) { cw0[u] = clsW[j0 + u]; cw1[u] = clsW[2304 + j0 + u]; }
    for (int s = 0; s < NT - 1; ++s) {
      wait2(flagS, s + 1, flagW, s);
      mfma_gates_t<0, 48, 72>(Wl, 4608,
                              nullptr, 0,
                              SUBWu + (long)(s & 3) * (NB * 768), 768,
                              H2Su + (long)(s & 1) * (NB * 384), 384, gl);
      __syncthreads();
      float p0 = 0.f, p1 = 0.f;
      float h2v[2], c2v[2];
      #pragma unroll
      for (int u = 0; u < 2; ++u) {
        int col = 4 * (jj + u);
        float vi = gl[b][col + 0] + bv[u][0];
        float vf = gl[b][col + 1] + bv[u][1];
        float vg = gl[b][col + 2] + bv[u][2];
        float vo = gl[b][col + 3] + bv[u][3];
        float si = fast_sig(vi), sf = fast_sig(vf), so = fast_sig(vo);
        float tg = fast_tanh(vg);
        c2v[u] = sf * cst[u] + si * tg;
        h2v[u] = so * fast_tanh(c2v[u]);
        p0 += h2v[u] * cw0[u];
        p1 += h2v[u] * cw1[u];
      }
      int g = gp[s];
      bool push = (g >= 1);
      #pragma unroll
      for (int u = 0; u < 2; ++u) {
        cst[u]  = push ? c2v[u] : cst[u];
        hreg[u] = push ? h2v[u] : hreg[u];
      }
      ustore(H2Su + (long)((s + 1) & 1) * (NB * 384) + b * 384 + (j0 >> 1),
             pack2(hreg[0], hreg[1]));
      p0 += __shfl_down(p0, 1); p1 += __shfl_down(p1, 1);
      p0 += __shfl_down(p0, 2); p1 += __shfl_down(p1, 2);
      if ((tid & 3) == 0) {
        int bb = tid >> 2;
        atomicAdd(&out[((long)bb * NT + s + 1) * 2 + 0], p0);
        atomicAdd(&out[((long)bb * NT + s + 1) * 2 + 1], p1);
      }
      if (s < NT - 2) arrive_flag(flagW + nt * FPAD);
    }
  }
}

// ---------------------------------------------------------------------------
// Host launcher
// ---------------------------------------------------------------------------
extern "C" void kernel_launch(void* const* d_in, const int* in_sizes, int n_in,
                              void* d_out, int out_size, void* d_ws, size_t ws_size,
                              hipStream_t stream)
{
  const float* x     = (const float*)d_in[0];
  const int*   golds = (const int*)d_in[1];
  const float* WihF  = (const float*)d_in[2];
  const float* WhhF  = (const float*)d_in[3];
  const float* bF    = (const float*)d_in[4];
  const float* WihB  = (const float*)d_in[5];
  const float* WhhB  = (const float*)d_in[6];
  const float* bB    = (const float*)d_in[7];
  const float* WihS  = (const float*)d_in[8];
  const float* WhhS  = (const float*)d_in[9];
  const float* bS    = (const float*)d_in[10];
  const float* WihW  = (const float*)d_in[11];
  const float* WhhW  = (const float*)d_in[12];
  const float* bW    = (const float*)d_in[13];
  const float* clsW  = (const float*)d_in[14];
  const float* clsb  = (const float*)d_in[15];
  float* out = (float*)d_out;

  // workspace layout (bytes)
  const size_t OFF_X16  = 0;                   // 25165824
  const size_t OFF_WF   = 25165824;            //  9437184
  const size_t OFF_WB   = 34603008;            //  9437184
  const size_t OFF_WS   = 44040192;            // 14155776
  const size_t OFF_WW   = 58195968;            // 14155776
  const size_t OFF_L16  = 72351744;            // 50331648
  const size_t OFF_H16  = 122683392;           //   393216
  const size_t OFF_H1S  = 123076608;           //   196608
  const size_t OFF_H2S  = 123273216;           //   196608
  const size_t OFF_SUBW = 123469824;           //   786432 (4-deep ring)
  const size_t OFF_FLG  = 124256256;           //    49152 (4*96*128B)
  const size_t WS_NEEDED = 124305408;

  if (ws_size < WS_NEEDED) {
    fill_sentinel<<<(out_size + 255) / 256, 256, 0, stream>>>(out, out_size, 12345.f);
    return;
  }

  char* ws = (char*)d_ws;
  __hip_bfloat16* X16  = (__hip_bfloat16*)(ws + OFF_X16);
  __hip_bfloat16* WF   = (__hip_bfloat16*)(ws + OFF_WF);
  __hip_bfloat16* WB   = (__hip_bfloat16*)(ws + OFF_WB);
  __hip_bfloat16* WSp  = (__hip_bfloat16*)(ws + OFF_WS);
  __hip_bfloat16* WWp  = (__hip_bfloat16*)(ws + OFF_WW);
  __hip_bfloat16* L16  = (__hip_bfloat16*)(ws + OFF_L16);
  unsigned*       H16u = (unsigned*)(ws + OFF_H16);
  unsigned*       H1Su = (unsigned*)(ws + OFF_H1S);
  unsigned*       H2Su = (unsigned*)(ws + OFF_H2S);
  unsigned*       SUBWu= (unsigned*)(ws + OFF_SUBW);
  int*            flags= (int*)(ws + OFF_FLG);

  // setup: pack weights, convert x, zero states + flags
  pack_w_kernel<<<2048, 256, 0, stream>>>(WihF, WhhF, WF, 768);
  pack_w_kernel<<<2048, 256, 0, stream>>>(WihB, WhhB, WB, 768);
  pack_w_kernel<<<2048, 256, 0, stream>>>(WihS, WhhS, WSp, 1536);
  pack_w_kernel<<<2048, 256, 0, stream>>>(WihW, WhhW, WWp, 1536);
  cvt_bf16_kernel<<<2048, 256, 0, stream>>>(x, X16, (long)NB * NT * HD);
  hipMemsetAsync(ws + OFF_H16, 0, WS_NEEDED - OFF_H16, stream);

  // phase 1: persistent BiLSTM (256 internal flag-sync steps)
  bilstm_persist<<<192, 256, 0, stream>>>(X16, WF, WB, bF, bB, H16u, L16, flags);

  // cls x-part + pred0 (full overwrite of out)
  clsx_kernel<<<NT, 256, 0, stream>>>(L16, clsW, clsb, out);

  // phase 2: persistent stack-LSTM, subword/word chains pipelined
  stack_persist<<<192, 256, 0, stream>>>(L16, WSp, WWp, bS, bW, golds, clsW,
                                         H1Su, H2Su, SUBWu, out, flags);
}

// Round 8
// 4732.902 us; speedup vs baseline: 2.8816x; 2.8816x over previous
//
#include <hip/hip_runtime.h>
#include <hip/hip_bf16.h>

typedef __attribute__((ext_vector_type(8))) short bf16x8;
typedef __attribute__((ext_vector_type(4))) float f32x4;
typedef __attribute__((ext_vector_type(4))) unsigned u32x4;

#define HD   768
#define NB   64
#define NT   256
#define NGATE 3072   // 4*HD
#define FPAD 32      // flag padding: 32 ints = 128 B (one cache line)

__device__ __forceinline__ float fast_sig(float x) { return 1.f / (1.f + __expf(-x)); }
__device__ __forceinline__ float fast_tanh(float x) {
  float t = __expf(-2.f * fabsf(x));
  float r = (1.f - t) / (1.f + t);
  return x < 0.f ? -r : r;
}
__device__ __forceinline__ float bf2f(unsigned short u) {
  union { unsigned i; float f; } v; v.i = ((unsigned)u) << 16; return v.f;
}
__device__ __forceinline__ unsigned short f2bfu(float f) {
  union { __hip_bfloat16 b; unsigned short u; } c;
  c.b = __float2bfloat16(f);
  return c.u;
}
__device__ __forceinline__ unsigned pack2(float a, float b) {
  return (unsigned)f2bfu(a) | ((unsigned)f2bfu(b) << 16);
}

// ---------------------------------------------------------------------------
// Coherent-path primitives (LLC, bypass non-cross-coherent per-XCD L2).
// NO buffer_wbl2 / buffer_inv anywhere in the persistent loops.
// ---------------------------------------------------------------------------
__device__ __forceinline__ int aload(int* p) {
  return __hip_atomic_load(p, __ATOMIC_RELAXED, __HIP_MEMORY_SCOPE_AGENT);
}
__device__ __forceinline__ void ustore(unsigned* p, unsigned v) {
  __hip_atomic_store(p, v, __ATOMIC_RELAXED, __HIP_MEMORY_SCOPE_AGENT);
}
// wide coherent load: 16B, always served at the coherent point
__device__ __forceinline__ u32x4 cload16(const char* p) {
  u32x4 r;
  asm volatile("global_load_dwordx4 %0, %1, off sc0 sc1"
               : "=v"(r) : "v"(p) : "memory");
  return r;
}

// Publish: drain this thread's (write-through) stores, block barrier, flag RMW.
__device__ __forceinline__ void arrive_flag(int* f) {
  asm volatile("s_waitcnt vmcnt(0)" ::: "memory");
  __syncthreads();
  if (threadIdx.x == 0)
    __hip_atomic_fetch_add(f, 1, __ATOMIC_RELAXED, __HIP_MEMORY_SCOPE_AGENT);
}

// Wait until all 96 flags in fa >= ta AND (fb: all 96 flags in fb >= tb).
// Threads 0..95 poll fa, 128..223 poll fb. Bounded spin -> fast-fail.
__device__ __forceinline__ void wait2(int* fa, int ta, int* fb, int tb) {
  int tid = threadIdx.x;
  int* p = nullptr; int tgt = 0;
  if (tid < 96)                            { p = fa + tid * FPAD;         tgt = ta; }
  else if (fb && tid >= 128 && tid < 224)  { p = fb + (tid - 128) * FPAD; tgt = tb; }
  if (p && tgt > 0) {
    int guard = 0;
    while (aload(p) < tgt) {
      __builtin_amdgcn_s_sleep(1);
      if (++guard > (1 << 17)) break;      // deadlock -> fast wrong answer, not hang
    }
  }
  __syncthreads();                         // all flags observed; compiler fence
}

// ---------------------------------------------------------------------------
// MFMA-fragment exchange layout ("frag"): 16B chunk (it, w, lh, lr) at byte
//   ((it*4 + w)*64 + (lh*16 + lr)) * 16   [it = k/32 within the frag range]
// Consumer lane l of wave w reads chunk (it, w, l): 64 lanes -> 1KB contiguous.
// Producer of k-pair (j, j+1) for batch row b writes one dword:
// ---------------------------------------------------------------------------
__device__ __forceinline__ int frag_dw(int b, int j) {
  return (((((j >> 5) * 4 + (b >> 4)) * 4 + ((j >> 3) & 3)) * 16 + (b & 15)) * 4)
         + ((j & 7) >> 1);
}

// ---------------------------------------------------------------------------
// Load a 32-row weight slice into LDS, XOR-swizzled:
//   lds_byte(r, cb) = r*K*2 + (cb ^ ((r&7)<<4))
// ---------------------------------------------------------------------------
__device__ __forceinline__ void load_W_lds(unsigned short* Wl,
                                           const __hip_bfloat16* Wg,
                                           int n_base, int K)
{
  int chunksPerRow = (K * 2) / 16;
  int total = 32 * chunksPerRow;
  for (int idx = threadIdx.x; idx < total; idx += 256) {
    int r  = idx / chunksPerRow;
    int cb = (idx % chunksPerRow) * 16;
    bf16x8 v = *(const bf16x8*)((const char*)(Wg + (long)(n_base + r) * K) + cb);
    *(bf16x8*)((char*)Wl + (long)r * (K * 2) + (cb ^ ((r & 7) << 4))) = v;
  }
}

// ---------------------------------------------------------------------------
// Frag-range MFMA: CF iterations (multiple of 12) reading a frag buffer with
// wide coherent loads, double-buffered 12-deep, counted vmcnt (safe even with
// unrelated cached loads outstanding: vmcnt(N) is conservative).
// ---------------------------------------------------------------------------
template<int CF>
__device__ __forceinline__ void mfma_frag_range(
    const char* Fbase, int l, int w,
    const char* w0, const char* w1, int xr, int kk, int kbase,
    f32x4& acc0, f32x4& acc1)
{
  const char* fp = Fbase + (size_t)(w * 64 + l) * 16;
  u32x4 st[2][12];
  #pragma unroll
  for (int i = 0; i < 12; ++i)
    st[0][i] = cload16(fp + (size_t)i * 4096);
  #pragma unroll
  for (int c = 0; c < CF / 12; ++c) {
    if (c + 1 < CF / 12) {
      #pragma unroll
      for (int i = 0; i < 12; ++i)
        st[(c + 1) & 1][i] = cload16(fp + (size_t)((c + 1) * 12 + i) * 4096);
      asm volatile("s_waitcnt vmcnt(12)" ::: "memory");
    } else {
      asm volatile("s_waitcnt vmcnt(0)" ::: "memory");
    }
    __builtin_amdgcn_sched_barrier(0);
    #pragma unroll
    for (int i = 0; i < 12; ++i) {
      int it = kbase + c * 12 + i;
      int o = ((it * 32 + kk) * 2) ^ xr;
      bf16x8 av = __builtin_bit_cast(bf16x8, st[c & 1][i]);
      bf16x8 bv0 = *(const bf16x8*)(w0 + o);
      bf16x8 bv1 = *(const bf16x8*)(w1 + o);
      acc0 = __builtin_amdgcn_mfma_f32_16x16x32_bf16(av, bv0, acc0, 0, 0, 0);
      acc1 = __builtin_amdgcn_mfma_f32_16x16x32_bf16(av, bv1, acc1, 0, 0, 0);
    }
  }
}

// Cached-A range (read-only data; compiler-managed loads & waits)
__device__ __forceinline__ void mfma_cached_range(
    const __hip_bfloat16* a0p, int C0,
    const char* w0, const char* w1, int xr, int kk,
    f32x4& acc0, f32x4& acc1)
{
  #pragma unroll 4
  for (int it = 0; it < C0; ++it) {
    bf16x8 av = *(const bf16x8*)(a0p + it * 32 + kk);
    int o = ((it * 32 + kk) * 2) ^ xr;
    bf16x8 bv0 = *(const bf16x8*)(w0 + o);
    bf16x8 bv1 = *(const bf16x8*)(w1 + o);
    acc0 = __builtin_amdgcn_mfma_f32_16x16x32_bf16(av, bv0, acc0, 0, 0, 0);
    acc1 = __builtin_amdgcn_mfma_f32_16x16x32_bf16(av, bv1, acc1, 0, 0, 0);
  }
}

// ---------------------------------------------------------------------------
// Setup kernels
// ---------------------------------------------------------------------------
__global__ void cvt_bf16_kernel(const float* __restrict__ src,
                                __hip_bfloat16* __restrict__ dst, long n)
{
  long i = (long)blockIdx.x * blockDim.x + threadIdx.x;
  long stride = (long)gridDim.x * blockDim.x;
  for (; i < n; i += stride) dst[i] = __float2bfloat16(src[i]);
}

// dst[n'][k], n' = j*4 + g; k < Kih -> Wih, else Whh
__global__ void pack_w_kernel(const float* __restrict__ Wih,
                              const float* __restrict__ Whh,
                              __hip_bfloat16* __restrict__ dst, int Kih)
{
  int K = Kih + HD;
  long total = (long)NGATE * K;
  long stride = (long)gridDim.x * blockDim.x;
  for (long idx = (long)blockIdx.x * blockDim.x + threadIdx.x; idx < total; idx += stride) {
    int np = (int)(idx / K), k = (int)(idx % K);
    int j = np >> 2, g = np & 3;
    int n = g * HD + j;
    float v = (k < Kih) ? Wih[(long)n * Kih + k] : Whh[(long)n * HD + (k - Kih)];
    dst[idx] = __float2bfloat16(v);
  }
}

__global__ void fill_sentinel(float* out, int n, float v)
{
  int i = blockIdx.x * blockDim.x + threadIdx.x;
  if (i < n) out[i] = v;
}

// ---------------------------------------------------------------------------
// Phase 1 persistent: BiLSTM, 192 blocks (0-95 fwd, 96-191 bwd), 256 steps.
// W-slice in LDS; c-state in registers; h exchanged via frag-layout LLC
// buffers (write-through dword stores, wide coherent reads). No fences.
// ---------------------------------------------------------------------------
__global__ __launch_bounds__(256, 1) void bilstm_persist(
    const __hip_bfloat16* __restrict__ X16,   // [64][256][768]
    const __hip_bfloat16* __restrict__ WF,
    const __hip_bfloat16* __restrict__ WB,
    const float* __restrict__ bF, const float* __restrict__ bB,
    unsigned* __restrict__ H16u,              // [2 par][2 dir] frag 98304B
    __hip_bfloat16* __restrict__ L16,         // [64][256][1536]
    int* __restrict__ flags)                  // [2 dir][96*FPAD]
{
  __shared__ unsigned short Wl[32 * 1536];    // 96 KiB
  __shared__ float gl[64][33];
  int blk = blockIdx.x, dir = blk / 96, nt = blk % 96;
  load_W_lds(Wl, dir ? WB : WF, nt * 32, 1536);
  const float* bias = dir ? bB : bF;
  int* myflags = flags + dir * 96 * FPAD;
  int tid = threadIdx.x;
  unsigned* L16u = (unsigned*)L16;

  int w = tid >> 6, l = tid & 63, lr = l & 15, lh = l >> 4;
  const char* w0 = (const char*)Wl + lr * 3072;
  const char* w1 = (const char*)Wl + (16 + lr) * 3072;
  int xr = (lr & 7) << 4;
  int kk = 8 * lh;
  int bA = 16 * w + lr;

  int e0 = tid * 2;
  int b = e0 >> 3, jj = e0 & 7;        // jj even
  int j0 = nt * 8 + jj;
  float bv[2][4];
  #pragma unroll
  for (int u = 0; u < 2; ++u) {
    bv[u][0] = bias[j0 + u];          bv[u][1] = bias[HD + j0 + u];
    bv[u][2] = bias[2 * HD + j0 + u]; bv[u][3] = bias[3 * HD + j0 + u];
  }
  int fdw = frag_dw(b, j0);            // h occupies frag k-range [0,768)
  float cst[2] = {0.f, 0.f};
  __syncthreads();

  for (int s = 0; s < NT; ++s) {
    int par = s & 1;
    int t = dir ? (NT - 1 - s) : s;
    if (s > 0) wait2(myflags, s, nullptr, 0);
    f32x4 acc0 = {0.f, 0.f, 0.f, 0.f};
    f32x4 acc1 = {0.f, 0.f, 0.f, 0.f};
    mfma_cached_range(X16 + (long)t * HD + (long)bA * (NT * HD), 24,
                      w0, w1, xr, kk, acc0, acc1);
    mfma_frag_range<24>((const char*)(H16u + (long)(par * 2 + dir) * 24576),
                        l, w, w0, w1, xr, kk, 24, acc0, acc1);
    #pragma unroll
    for (int r = 0; r < 4; ++r) {
      gl[16 * w + 4 * lh + r][lr]      = acc0[r];
      gl[16 * w + 4 * lh + r][16 + lr] = acc1[r];
    }
    __syncthreads();
    float hv[2];
    #pragma unroll
    for (int u = 0; u < 2; ++u) {
      int col = 4 * (jj + u);
      float vi = gl[b][col + 0] + bv[u][0];
      float vf = gl[b][col + 1] + bv[u][1];
      float vg = gl[b][col + 2] + bv[u][2];
      float vo = gl[b][col + 3] + bv[u][3];
      float si = fast_sig(vi), sf = fast_sig(vf), so = fast_sig(vo);
      float tg = fast_tanh(vg);
      float c = sf * cst[u] + si * tg;
      cst[u] = c;
      hv[u] = so * fast_tanh(c);
    }
    unsigned pk = pack2(hv[0], hv[1]);
    ustore(H16u + (long)((par ^ 1) * 2 + dir) * 24576 + fdw, pk);
    L16u[((long)b * NT + t) * 768 + dir * 384 + (j0 >> 1)] = pk;  // cached store (kernel-end flush)
    if (s < NT - 1) arrive_flag(myflags + nt * FPAD);
  }
}

// ---------------------------------------------------------------------------
// cls x-part (vectorized) + pred0
// ---------------------------------------------------------------------------
__global__ __launch_bounds__(256) void clsx_kernel(
    const __hip_bfloat16* __restrict__ L16,
    const float* __restrict__ clsW, const float* __restrict__ clsb,
    float* __restrict__ out)
{
  int t = blockIdx.x;
  int tid = threadIdx.x;
  if (tid >= 128) return;
  int b = tid >> 1, o = tid & 1;
  if (t == 0) {
    out[((long)b * NT) * 2 + o] = o ? 1.f : -1.f;
    return;
  }
  const bf16x8* xp = (const bf16x8*)(L16 + ((long)b * NT + t) * 1536);
  const float* w = clsW + o * 2304 + HD;
  float s = clsb[o];
  for (int k = 0; k < 192; ++k) {
    bf16x8 v = xp[k];
    #pragma unroll
    for (int e = 0; e < 8; ++e)
      s += bf2f((unsigned short)v[e]) * w[k * 8 + e];
  }
  out[((long)b * NT + t) * 2 + o] = s;
}

// ---------------------------------------------------------------------------
// Phase 2 persistent: 192 blocks (0-95 subword chain, 96-191 word chain),
// producer-consumer via 4-deep SUBW frag ring + flag arrays.
//   subword step s: needs flagS>=s (h1 exchange), flagW>=s-3 (ring free)
//   word    step s: needs flagS>=s+1 (SUBW[s] ready), flagW>=s (h2 exchange)
// All cross-block data in frag layout through the LLC. No fences.
// ---------------------------------------------------------------------------
__global__ __launch_bounds__(256, 1) void stack_persist(
    const __hip_bfloat16* __restrict__ L16,
    const __hip_bfloat16* __restrict__ WS,
    const __hip_bfloat16* __restrict__ WW,
    const float* __restrict__ bS, const float* __restrict__ bW,
    const int* __restrict__ golds,
    const float* __restrict__ clsW,
    unsigned* __restrict__ H1Su,   // [2] frag 98304B
    unsigned* __restrict__ H2Su,   // [2] frag 98304B
    unsigned* __restrict__ SUBWu,  // [4] frag 196608B ring (h1 k<768, c1 k 768..1536)
    float* __restrict__ out,
    int* __restrict__ flags)       // [+2*96*FPAD: S] [+3*96*FPAD: W]
{
  __shared__ unsigned short Wl[32 * 2304];  // 144 KiB
  __shared__ float gl[64][33];
  int blk = blockIdx.x, role = blk / 96, nt = blk % 96;
  int* flagS = flags + 2 * 96 * FPAD;
  int* flagW = flags + 3 * 96 * FPAD;
  const float* bias = role ? bW : bS;
  load_W_lds(Wl, role ? WW : WS, nt * 32, 2304);
  int tid = threadIdx.x;

  int w = tid >> 6, l = tid & 63, lr = l & 15, lh = l >> 4;
  const char* w0 = (const char*)Wl + lr * 4608;
  const char* w1 = (const char*)Wl + (16 + lr) * 4608;
  int xr = (lr & 7) << 4;
  int kk = 8 * lh;
  int bA = 16 * w + lr;

  int e0 = tid * 2;
  int b = e0 >> 3, jj = e0 & 7;        // jj even
  int j0 = nt * 8 + jj;
  float bv[2][4];
  #pragma unroll
  for (int u = 0; u < 2; ++u) {
    bv[u][0] = bias[j0 + u];          bv[u][1] = bias[HD + j0 + u];
    bv[u][2] = bias[2 * HD + j0 + u]; bv[u][3] = bias[3 * HD + j0 + u];
  }
  const int* gp = golds + b * NT + 1;   // gp[s] = golds[b][s+1]
  int fdw_h = frag_dw(b, j0);           // k-offset within a 24-iter (768) frag
  float cst[2] = {0.f, 0.f};
  float hreg[2] = {0.f, 0.f};
  __syncthreads();

  if (role == 0) {
    // ---- subword chain ----
    int fdw_c = frag_dw(b, 768 + j0);   // c1 goes at k 768.. in SUBW frag
    for (int s = 0; s < NT - 1; ++s) {
      wait2(flagS, s, flagW, s - 3);
      f32x4 acc0 = {0.f, 0.f, 0.f, 0.f};
      f32x4 acc1 = {0.f, 0.f, 0.f, 0.f};
      mfma_cached_range(L16 + (long)s * 1536 + (long)bA * (NT * 1536), 48,
                        w0, w1, xr, kk, acc0, acc1);
      mfma_frag_range<24>((const char*)(H1Su + (long)(s & 1) * 24576),
                          l, w, w0, w1, xr, kk, 48, acc0, acc1);
      #pragma unroll
      for (int r = 0; r < 4; ++r) {
        gl[16 * w + 4 * lh + r][lr]      = acc0[r];
        gl[16 * w + 4 * lh + r][16 + lr] = acc1[r];
      }
      __syncthreads();
      float h1v[2], c1v[2];
      #pragma unroll
      for (int u = 0; u < 2; ++u) {
        int col = 4 * (jj + u);
        float vi = gl[b][col + 0] + bv[u][0];
        float vf = gl[b][col + 1] + bv[u][1];
        float vg = gl[b][col + 2] + bv[u][2];
        float vo = gl[b][col + 3] + bv[u][3];
        float si = fast_sig(vi), sf = fast_sig(vf), so = fast_sig(vo);
        float tg = fast_tanh(vg);
        c1v[u] = sf * cst[u] + si * tg;
        h1v[u] = so * fast_tanh(c1v[u]);
      }
      int g = gp[s];
      bool push = (g == 0);
      unsigned pkh = pack2(h1v[0], h1v[1]);
      unsigned pkc = pack2(c1v[0], c1v[1]);
      unsigned* sb = SUBWu + (long)(s & 3) * 49152;
      ustore(sb + fdw_h, pkh);
      ustore(sb + fdw_c, pkc);
      ustore(H1Su + (long)((s + 1) & 1) * 24576 + fdw_h, push ? pkh : 0u);
      cst[0] = push ? c1v[0] : 0.f;
      cst[1] = push ? c1v[1] : 0.f;
      arrive_flag(flagS + nt * FPAD);
    }
  } else {
    // ---- word chain ----
    float cw0[2], cw1[2];
    #pragma unroll
    for (int u = 0; u < 2; ++u) { cw0[u] = clsW[j0 + u]; cw1[u] = clsW[2304 + j0 + u]; }
    for (int s = 0; s < NT - 1; ++s) {
      wait2(flagS, s + 1, flagW, s);
      f32x4 acc0 = {0.f, 0.f, 0.f, 0.f};
      f32x4 acc1 = {0.f, 0.f, 0.f, 0.f};
      mfma_frag_range<48>((const char*)(SUBWu + (long)(s & 3) * 49152),
                          l, w, w0, w1, xr, kk, 0, acc0, acc1);
      mfma_frag_range<24>((const char*)(H2Su + (long)(s & 1) * 24576),
                          l, w, w0, w1, xr, kk, 48, acc0, acc1);
      #pragma unroll
      for (int r = 0; r < 4; ++r) {
        gl[16 * w + 4 * lh + r][lr]      = acc0[r];
        gl[16 * w + 4 * lh + r][16 + lr] = acc1[r];
      }
      __syncthreads();
      float p0 = 0.f, p1 = 0.f;
      float h2v[2], c2v[2];
      #pragma unroll
      for (int u = 0; u < 2; ++u) {
        int col = 4 * (jj + u);
        float vi = gl[b][col + 0] + bv[u][0];
        float vf = gl[b][col + 1] + bv[u][1];
        float vg = gl[b][col + 2] + bv[u][2];
        float vo = gl[b][col + 3] + bv[u][3];
        float si = fast_sig(vi), sf = fast_sig(vf), so = fast_sig(vo);
        float tg = fast_tanh(vg);
        c2v[u] = sf * cst[u] + si * tg;
        h2v[u] = so * fast_tanh(c2v[u]);
        p0 += h2v[u] * cw0[u];
        p1 += h2v[u] * cw1[u];
      }
      int g = gp[s];
      bool push = (g >= 1);
      #pragma unroll
      for (int u = 0; u < 2; ++u) {
        cst[u]  = push ? c2v[u] : cst[u];
        hreg[u] = push ? h2v[u] : hreg[u];
      }
      ustore(H2Su + (long)((s + 1) & 1) * 24576 + fdw_h, pack2(hreg[0], hreg[1]));
      p0 += __shfl_down(p0, 1); p1 += __shfl_down(p1, 1);
      p0 += __shfl_down(p0, 2); p1 += __shfl_down(p1, 2);
      if ((tid & 3) == 0) {
        int bb = tid >> 2;
        atomicAdd(&out[((long)bb * NT + s + 1) * 2 + 0], p0);
        atomicAdd(&out[((long)bb * NT + s + 1) * 2 + 1], p1);
      }
      if (s < NT - 2) arrive_flag(flagW + nt * FPAD);
    }
  }
}

// ---------------------------------------------------------------------------
// Host launcher
// ---------------------------------------------------------------------------
extern "C" void kernel_launch(void* const* d_in, const int* in_sizes, int n_in,
                              void* d_out, int out_size, void* d_ws, size_t ws_size,
                              hipStream_t stream)
{
  const float* x     = (const float*)d_in[0];
  const int*   golds = (const int*)d_in[1];
  const float* WihF  = (const float*)d_in[2];
  const float* WhhF  = (const float*)d_in[3];
  const float* bF    = (const float*)d_in[4];
  const float* WihB  = (const float*)d_in[5];
  const float* WhhB  = (const float*)d_in[6];
  const float* bB    = (const float*)d_in[7];
  const float* WihS  = (const float*)d_in[8];
  const float* WhhS  = (const float*)d_in[9];
  const float* bS    = (const float*)d_in[10];
  const float* WihW  = (const float*)d_in[11];
  const float* WhhW  = (const float*)d_in[12];
  const float* bW    = (const float*)d_in[13];
  const float* clsW  = (const float*)d_in[14];
  const float* clsb  = (const float*)d_in[15];
  float* out = (float*)d_out;

  // workspace layout (bytes)
  const size_t OFF_X16  = 0;                   // 25165824
  const size_t OFF_WF   = 25165824;            //  9437184
  const size_t OFF_WB   = 34603008;            //  9437184
  const size_t OFF_WS   = 44040192;            // 14155776
  const size_t OFF_WW   = 58195968;            // 14155776
  const size_t OFF_L16  = 72351744;            // 50331648
  const size_t OFF_H16  = 122683392;           //   393216 (frag [2][2])
  const size_t OFF_H1S  = 123076608;           //   196608 (frag [2])
  const size_t OFF_H2S  = 123273216;           //   196608 (frag [2])
  const size_t OFF_SUBW = 123469824;           //   786432 (frag ring [4])
  const size_t OFF_FLG  = 124256256;           //    49152 (4*96*128B)
  const size_t WS_NEEDED = 124305408;

  if (ws_size < WS_NEEDED) {
    fill_sentinel<<<(out_size + 255) / 256, 256, 0, stream>>>(out, out_size, 12345.f);
    return;
  }

  char* ws = (char*)d_ws;
  __hip_bfloat16* X16  = (__hip_bfloat16*)(ws + OFF_X16);
  __hip_bfloat16* WF   = (__hip_bfloat16*)(ws + OFF_WF);
  __hip_bfloat16* WB   = (__hip_bfloat16*)(ws + OFF_WB);
  __hip_bfloat16* WSp  = (__hip_bfloat16*)(ws + OFF_WS);
  __hip_bfloat16* WWp  = (__hip_bfloat16*)(ws + OFF_WW);
  __hip_bfloat16* L16  = (__hip_bfloat16*)(ws + OFF_L16);
  unsigned*       H16u = (unsigned*)(ws + OFF_H16);
  unsigned*       H1Su = (unsigned*)(ws + OFF_H1S);
  unsigned*       H2Su = (unsigned*)(ws + OFF_H2S);
  unsigned*       SUBWu= (unsigned*)(ws + OFF_SUBW);
  int*            flags= (int*)(ws + OFF_FLG);

  // setup: pack weights, convert x, zero states + flags
  pack_w_kernel<<<2048, 256, 0, stream>>>(WihF, WhhF, WF, 768);
  pack_w_kernel<<<2048, 256, 0, stream>>>(WihB, WhhB, WB, 768);
  pack_w_kernel<<<2048, 256, 0, stream>>>(WihS, WhhS, WSp, 1536);
  pack_w_kernel<<<2048, 256, 0, stream>>>(WihW, WhhW, WWp, 1536);
  cvt_bf16_kernel<<<2048, 256, 0, stream>>>(x, X16, (long)NB * NT * HD);
  hipMemsetAsync(ws + OFF_H16, 0, WS_NEEDED - OFF_H16, stream);

  // phase 1: persistent BiLSTM (256 internal flag-sync steps)
  bilstm_persist<<<192, 256, 0, stream>>>(X16, WF, WB, bF, bB, H16u, L16, flags);

  // cls x-part + pred0 (full overwrite of out)
  clsx_kernel<<<NT, 256, 0, stream>>>(L16, clsW, clsb, out);

  // phase 2: persistent stack-LSTM, subword/word chains pipelined
  stack_persist<<<192, 256, 0, stream>>>(L16, WSp, WWp, bS, bW, golds, clsW,
                                         H1Su, H2Su, SUBWu, out, flags);
}

// Round 9
// 4056.333 us; speedup vs baseline: 3.3623x; 1.1668x over previous
//
#include <hip/hip_runtime.h>
#include <hip/hip_bf16.h>

typedef __attribute__((ext_vector_type(8))) short bf16x8;
typedef __attribute__((ext_vector_type(4))) float f32x4;
typedef __attribute__((ext_vector_type(4))) unsigned u32x4;

#define HD   768
#define NB   64
#define NT   256
#define NGATE 3072   // 4*HD
#define FPAD 32      // flag padding: 32 ints = 128 B (one cache line)

__device__ __forceinline__ float fast_sig(float x) { return 1.f / (1.f + __expf(-x)); }
__device__ __forceinline__ float fast_tanh(float x) {
  float t = __expf(-2.f * fabsf(x));
  float r = (1.f - t) / (1.f + t);
  return x < 0.f ? -r : r;
}
__device__ __forceinline__ float bf2f(unsigned short u) {
  union { unsigned i; float f; } v; v.i = ((unsigned)u) << 16; return v.f;
}
__device__ __forceinline__ unsigned short f2bfu(float f) {
  union { __hip_bfloat16 b; unsigned short u; } c;
  c.b = __float2bfloat16(f);
  return c.u;
}
__device__ __forceinline__ unsigned pack2(float a, float b) {
  return (unsigned)f2bfu(a) | ((unsigned)f2bfu(b) << 16);
}

// ---------------------------------------------------------------------------
// Coherent-path primitives (LLC, bypass non-cross-coherent per-XCD L2).
// NO buffer_wbl2 / buffer_inv anywhere in the persistent loops.
// ---------------------------------------------------------------------------
__device__ __forceinline__ int aload(int* p) {
  return __hip_atomic_load(p, __ATOMIC_RELAXED, __HIP_MEMORY_SCOPE_AGENT);
}
__device__ __forceinline__ void ustore(unsigned* p, unsigned v) {
  __hip_atomic_store(p, v, __ATOMIC_RELAXED, __HIP_MEMORY_SCOPE_AGENT);
}
// wide coherent load: 16B, always served at the coherent point
__device__ __forceinline__ u32x4 cload16(const char* p) {
  u32x4 r;
  asm volatile("global_load_dwordx4 %0, %1, off sc0 sc1"
               : "=v"(r) : "v"(p) : "memory");
  return r;
}

// Publish: drain this thread's (write-through) stores, block barrier, flag RMW.
__device__ __forceinline__ void arrive_flag(int* f) {
  asm volatile("s_waitcnt vmcnt(0)" ::: "memory");
  __syncthreads();
  if (threadIdx.x == 0)
    __hip_atomic_fetch_add(f, 1, __ATOMIC_RELAXED, __HIP_MEMORY_SCOPE_AGENT);
}

// Wait until all 96 flags in fa >= ta AND (fb: all 96 flags in fb >= tb).
// Threads 0..95 poll fa, 128..223 poll fb. Bounded spin -> fast-fail.
__device__ __forceinline__ void wait2(int* fa, int ta, int* fb, int tb) {
  int tid = threadIdx.x;
  int* p = nullptr; int tgt = 0;
  if (tid < 96)                            { p = fa + tid * FPAD;         tgt = ta; }
  else if (fb && tid >= 128 && tid < 224)  { p = fb + (tid - 128) * FPAD; tgt = tb; }
  if (p && tgt > 0) {
    int guard = 0;
    while (aload(p) < tgt) {
      __builtin_amdgcn_s_sleep(1);
      if (++guard > (1 << 17)) break;      // deadlock -> fast wrong answer, not hang
    }
  }
  __syncthreads();                         // all flags observed; compiler fence
}

// ---------------------------------------------------------------------------
// MFMA-fragment exchange layout ("frag"): 16B chunk (it, rg, l) at byte
//   ((it*4 + rg)*64 + l) * 16      rg = batch rowgroup (b>>4), l = lane
// Consumer lane l of wave w (rowgroup w) reads chunk (it, w, l):
//   64 lanes -> 1KB contiguous. Producer of k-pair (j,j+1), batch b:
// ---------------------------------------------------------------------------
__device__ __forceinline__ int frag_dw(int b, int j) {
  return (((((j >> 5) * 4 + (b >> 4)) * 4 + ((j >> 3) & 3)) * 16 + (b & 15)) * 4)
         + ((j & 7) >> 1);
}

// ---------------------------------------------------------------------------
// W LDS swizzle, FULL-RANK: swz(r) = ((r&7)<<4) | (((r>>3)&3)<<7)
// bits 4-6 separate r&7; bits 7-8 separate the four 8-row groups.
// Row length (3072 / 4608 B) is a multiple of 512 -> XOR stays in-row.
// All 32 rows now have distinct bank phases (was 4-way aliased).
// ---------------------------------------------------------------------------
__device__ __forceinline__ int wswz(int r) {
  return ((r & 7) << 4) | (((r >> 3) & 3) << 7);
}

__device__ __forceinline__ void load_W_lds(unsigned short* Wl,
                                           const __hip_bfloat16* Wg,
                                           int n_base, int K)
{
  int chunksPerRow = (K * 2) / 16;
  int total = 32 * chunksPerRow;
  for (int idx = threadIdx.x; idx < total; idx += 256) {
    int r  = idx / chunksPerRow;
    int cb = (idx % chunksPerRow) * 16;
    bf16x8 v = *(const bf16x8*)((const char*)(Wg + (long)(n_base + r) * K) + cb);
    *(bf16x8*)((char*)Wl + (long)r * (K * 2) + (cb ^ wswz(r))) = v;
  }
}

// ---------------------------------------------------------------------------
// Cached-A MFMA range (read-only global data; compiler-managed pipelining)
// ---------------------------------------------------------------------------
__device__ __forceinline__ void mfma_cached(
    const __hip_bfloat16* a0p, int NIT,
    const char* w0, const char* w1, int xr0, int xr1, int kk,
    f32x4& acc0, f32x4& acc1)
{
  #pragma unroll 4
  for (int it = 0; it < NIT; ++it) {
    bf16x8 av = *(const bf16x8*)(a0p + it * 32 + kk);
    int oo = (it * 32 + kk) * 2;
    bf16x8 bv0 = *(const bf16x8*)(w0 + (oo ^ xr0));
    bf16x8 bv1 = *(const bf16x8*)(w1 + (oo ^ xr1));
    acc0 = __builtin_amdgcn_mfma_f32_16x16x32_bf16(av, bv0, acc0, 0, 0, 0);
    acc1 = __builtin_amdgcn_mfma_f32_16x16x32_bf16(av, bv1, acc1, 0, 0, 0);
  }
}

// ---------------------------------------------------------------------------
// Frag-range MFMA: CF its (multiple of 12) from a frag buffer via wide
// coherent loads, 12-deep double-buffered, counted vmcnt.
// ---------------------------------------------------------------------------
template<int CF>
__device__ __forceinline__ void mfma_frag(
    const char* Fbase, int l, int w,
    const char* w0, const char* w1, int xr0, int xr1, int kk, int kbase,
    f32x4& acc0, f32x4& acc1)
{
  const char* fp = Fbase + (size_t)(w * 64 + l) * 16;
  u32x4 st[2][12];
  #pragma unroll
  for (int i = 0; i < 12; ++i)
    st[0][i] = cload16(fp + (size_t)i * 4096);
  #pragma unroll
  for (int c = 0; c < CF / 12; ++c) {
    if (c + 1 < CF / 12) {
      #pragma unroll
      for (int i = 0; i < 12; ++i)
        st[(c + 1) & 1][i] = cload16(fp + (size_t)((c + 1) * 12 + i) * 4096);
      asm volatile("s_waitcnt vmcnt(12)" ::: "memory");
    } else {
      asm volatile("s_waitcnt vmcnt(0)" ::: "memory");
    }
    __builtin_amdgcn_sched_barrier(0);
    #pragma unroll
    for (int i = 0; i < 12; ++i) {
      int oo = ((kbase + c * 12 + i) * 32 + kk) * 2;
      bf16x8 av = __builtin_bit_cast(bf16x8, st[c & 1][i]);
      bf16x8 bv0 = *(const bf16x8*)(w0 + (oo ^ xr0));
      bf16x8 bv1 = *(const bf16x8*)(w1 + (oo ^ xr1));
      acc0 = __builtin_amdgcn_mfma_f32_16x16x32_bf16(av, bv0, acc0, 0, 0, 0);
      acc1 = __builtin_amdgcn_mfma_f32_16x16x32_bf16(av, bv1, acc1, 0, 0, 0);
    }
  }
}

// ---------------------------------------------------------------------------
// Fused setup: convert x to bf16 + pack all 4 weight matrices (one launch).
// ---------------------------------------------------------------------------
__device__ __forceinline__ void pack_seg(const float* Wih, const float* Whh,
                                         __hip_bfloat16* dst, int Kih,
                                         long id0, long stride)
{
  int K = Kih + HD;
  long total = (long)NGATE * K;
  for (long idx = id0; idx < total; idx += stride) {
    int np = (int)(idx / K), k = (int)(idx % K);
    int j = np >> 2, g = np & 3;
    int n = g * HD + j;
    float v = (k < Kih) ? Wih[(long)n * Kih + k] : Whh[(long)n * HD + (k - Kih)];
    dst[idx] = __float2bfloat16(v);
  }
}

__global__ void setup_kernel(
    const float* __restrict__ x,
    const float* __restrict__ WihF, const float* __restrict__ WhhF,
    const float* __restrict__ WihB, const float* __restrict__ WhhB,
    const float* __restrict__ WihS, const float* __restrict__ WhhS,
    const float* __restrict__ WihW, const float* __restrict__ WhhW,
    __hip_bfloat16* __restrict__ X16,
    __hip_bfloat16* __restrict__ WF, __hip_bfloat16* __restrict__ WB,
    __hip_bfloat16* __restrict__ WS, __hip_bfloat16* __restrict__ WW)
{
  long id0 = (long)blockIdx.x * blockDim.x + threadIdx.x;
  long stride = (long)gridDim.x * blockDim.x;
  for (long i = id0; i < (long)NB * NT * HD; i += stride)
    X16[i] = __float2bfloat16(x[i]);
  pack_seg(WihF, WhhF, WF, 768, id0, stride);
  pack_seg(WihB, WhhB, WB, 768, id0, stride);
  pack_seg(WihS, WhhS, WS, 1536, id0, stride);
  pack_seg(WihW, WhhW, WW, 1536, id0, stride);
}

__global__ void fill_sentinel(float* out, int n, float v)
{
  int i = blockIdx.x * blockDim.x + threadIdx.x;
  if (i < n) out[i] = v;
}

// ---------------------------------------------------------------------------
// Phase 1 persistent: BiLSTM, 192 blocks (0-95 fwd, 96-191 bwd), 256 steps.
// Prewait: X16 part (24 its, flag-independent) BEFORE the flag wait; only
// the 24 H-frag its sit on the cross-block dependency chain.
// ---------------------------------------------------------------------------
__global__ __launch_bounds__(256, 1) void bilstm_persist(
    const __hip_bfloat16* __restrict__ X16,   // [64][256][768]
    const __hip_bfloat16* __restrict__ WF,
    const __hip_bfloat16* __restrict__ WB,
    const float* __restrict__ bF, const float* __restrict__ bB,
    unsigned* __restrict__ H16u,              // [2 par][2 dir] frag 98304B
    __hip_bfloat16* __restrict__ L16,         // [64][256][1536]
    int* __restrict__ flags)                  // [2 dir][96*FPAD]
{
  __shared__ unsigned short Wl[32 * 1536];    // 96 KiB
  __shared__ float gl[64][33];
  int blk = blockIdx.x, dir = blk / 96, nt = blk % 96;
  load_W_lds(Wl, dir ? WB : WF, nt * 32, 1536);
  const float* bias = dir ? bB : bF;
  int* myflags = flags + dir * 96 * FPAD;
  int tid = threadIdx.x;
  unsigned* L16u = (unsigned*)L16;

  int w = tid >> 6, l = tid & 63, lr = l & 15, lh = l >> 4;
  const char* w0 = (const char*)Wl + lr * 3072;
  const char* w1 = (const char*)Wl + (16 + lr) * 3072;
  int xr0 = wswz(lr), xr1 = wswz(16 + lr);
  int kk = 8 * lh;
  int bA = 16 * w + lr;

  int e0 = tid * 2;
  int b = e0 >> 3, jj = e0 & 7;        // jj even
  int j0 = nt * 8 + jj;
  float bv[2][4];
  #pragma unroll
  for (int u = 0; u < 2; ++u) {
    bv[u][0] = bias[j0 + u];          bv[u][1] = bias[HD + j0 + u];
    bv[u][2] = bias[2 * HD + j0 + u]; bv[u][3] = bias[3 * HD + j0 + u];
  }
  int fdw = frag_dw(b, j0);
  float cst[2] = {0.f, 0.f};
  __syncthreads();

  for (int s = 0; s < NT; ++s) {
    int par = s & 1;
    int t = dir ? (NT - 1 - s) : s;
    f32x4 acc0 = {0.f, 0.f, 0.f, 0.f};
    f32x4 acc1 = {0.f, 0.f, 0.f, 0.f};
    // prewait: x-part (flag-independent)
    mfma_cached(X16 + (long)t * HD + (long)bA * (NT * HD), 24,
                w0, w1, xr0, xr1, kk, acc0, acc1);
    if (s > 0) wait2(myflags, s, nullptr, 0);
    // dependent: h-part from frag buffer
    mfma_frag<24>((const char*)(H16u + (long)(par * 2 + dir) * 24576),
                  l, w, w0, w1, xr0, xr1, kk, 24, acc0, acc1);
    #pragma unroll
    for (int r = 0; r < 4; ++r) {
      gl[16 * w + 4 * lh + r][lr]      = acc0[r];
      gl[16 * w + 4 * lh + r][16 + lr] = acc1[r];
    }
    __syncthreads();
    float hv[2];
    #pragma unroll
    for (int u = 0; u < 2; ++u) {
      int col = 4 * (jj + u);
      float vi = gl[b][col + 0] + bv[u][0];
      float vf = gl[b][col + 1] + bv[u][1];
      float vg = gl[b][col + 2] + bv[u][2];
      float vo = gl[b][col + 3] + bv[u][3];
      float si = fast_sig(vi), sf = fast_sig(vf), so = fast_sig(vo);
      float tg = fast_tanh(vg);
      float c = sf * cst[u] + si * tg;
      cst[u] = c;
      hv[u] = so * fast_tanh(c);
    }
    unsigned pk = pack2(hv[0], hv[1]);
    ustore(H16u + (long)((par ^ 1) * 2 + dir) * 24576 + fdw, pk);
    L16u[((long)b * NT + t) * 768 + dir * 384 + (j0 >> 1)] = pk;  // cached (kernel-end flush)
    if (s < NT - 1) arrive_flag(myflags + nt * FPAD);
  }
}

// ---------------------------------------------------------------------------
// cls x-part (vectorized) + pred0
// ---------------------------------------------------------------------------
__global__ __launch_bounds__(256) void clsx_kernel(
    const __hip_bfloat16* __restrict__ L16,
    const float* __restrict__ clsW, const float* __restrict__ clsb,
    float* __restrict__ out)
{
  int t = blockIdx.x;
  int tid = threadIdx.x;
  if (tid >= 128) return;
  int b = tid >> 1, o = tid & 1;
  if (t == 0) {
    out[((long)b * NT) * 2 + o] = o ? 1.f : -1.f;
    return;
  }
  const bf16x8* xp = (const bf16x8*)(L16 + ((long)b * NT + t) * 1536);
  const float* w = clsW + o * 2304 + HD;
  float s = clsb[o];
  for (int k = 0; k < 192; ++k) {
    bf16x8 v = xp[k];
    #pragma unroll
    for (int e = 0; e < 8; ++e)
      s += bf2f((unsigned short)v[e]) * w[k * 8 + e];
  }
  out[((long)b * NT + t) * 2 + o] = s;
}

// ---------------------------------------------------------------------------
// Phase 2 persistent: 192 blocks (0-95 subword chain, 96-191 word chain),
// producer-consumer via 4-deep SUBW frag ring + flag arrays.
//   subword step s: L16 part prewait; then flagS>=s & flagW>=s-3; H1 part.
//   word    step s: flagW>=s (self, fast); H2 part; flagS>=s+1; SUBW part.
// ---------------------------------------------------------------------------
__global__ __launch_bounds__(256, 1) void stack_persist(
    const __hip_bfloat16* __restrict__ L16,
    const __hip_bfloat16* __restrict__ WS,
    const __hip_bfloat16* __restrict__ WW,
    const float* __restrict__ bS, const float* __restrict__ bW,
    const int* __restrict__ golds,
    const float* __restrict__ clsW,
    unsigned* __restrict__ H1Su,   // [2] frag 98304B
    unsigned* __restrict__ H2Su,   // [2] frag 98304B
    unsigned* __restrict__ SUBWu,  // [4] frag 196608B ring (h1 k<768, c1 768..1536)
    float* __restrict__ out,
    int* __restrict__ flags)       // [+2*96*FPAD: S] [+3*96*FPAD: W]
{
  __shared__ unsigned short Wl[32 * 2304];  // 144 KiB
  __shared__ float gl[64][33];
  int blk = blockIdx.x, role = blk / 96, nt = blk % 96;
  int* flagS = flags + 2 * 96 * FPAD;
  int* flagW = flags + 3 * 96 * FPAD;
  const float* bias = role ? bW : bS;
  load_W_lds(Wl, role ? WW : WS, nt * 32, 2304);
  int tid = threadIdx.x;

  int w = tid >> 6, l = tid & 63, lr = l & 15, lh = l >> 4;
  const char* w0 = (const char*)Wl + lr * 4608;
  const char* w1 = (const char*)Wl + (16 + lr) * 4608;
  int xr0 = wswz(lr), xr1 = wswz(16 + lr);
  int kk = 8 * lh;
  int bA = 16 * w + lr;

  int e0 = tid * 2;
  int b = e0 >> 3, jj = e0 & 7;        // jj even
  int j0 = nt * 8 + jj;
  float bv[2][4];
  #pragma unroll
  for (int u = 0; u < 2; ++u) {
    bv[u][0] = bias[j0 + u];          bv[u][1] = bias[HD + j0 + u];
    bv[u][2] = bias[2 * HD + j0 + u]; bv[u][3] = bias[3 * HD + j0 + u];
  }
  const int* gp = golds + b * NT + 1;   // gp[s] = golds[b][s+1]
  int fdw_h = frag_dw(b, j0);
  float cst[2] = {0.f, 0.f};
  float hreg[2] = {0.f, 0.f};
  __syncthreads();

  if (role == 0) {
    // ---- subword chain ----
    int fdw_c = frag_dw(b, 768 + j0);   // c1 at k 768.. in SUBW frag
    for (int s = 0; s < NT - 1; ++s) {
      f32x4 acc0 = {0.f, 0.f, 0.f, 0.f};
      f32x4 acc1 = {0.f, 0.f, 0.f, 0.f};
      // prewait: L16 part (flag-independent)
      mfma_cached(L16 + (long)s * 1536 + (long)bA * (NT * 1536), 48,
                  w0, w1, xr0, xr1, kk, acc0, acc1);
      wait2(flagS, s, flagW, s - 3);
      // dependent: h1 part
      mfma_frag<24>((const char*)(H1Su + (long)(s & 1) * 24576),
                    l, w, w0, w1, xr0, xr1, kk, 48, acc0, acc1);
      #pragma unroll
      for (int r = 0; r < 4; ++r) {
        gl[16 * w + 4 * lh + r][lr]      = acc0[r];
        gl[16 * w + 4 * lh + r][16 + lr] = acc1[r];
      }
      __syncthreads();
      float h1v[2], c1v[2];
      #pragma unroll
      for (int u = 0; u < 2; ++u) {
        int col = 4 * (jj + u);
        float vi = gl[b][col + 0] + bv[u][0];
        float vf = gl[b][col + 1] + bv[u][1];
        float vg = gl[b][col + 2] + bv[u][2];
        float vo = gl[b][col + 3] + bv[u][3];
        float si = fast_sig(vi), sf = fast_sig(vf), so = fast_sig(vo);
        float tg = fast_tanh(vg);
        c1v[u] = sf * cst[u] + si * tg;
        h1v[u] = so * fast_tanh(c1v[u]);
      }
      int g = gp[s];
      bool push = (g == 0);
      unsigned pkh = pack2(h1v[0], h1v[1]);
      unsigned pkc = pack2(c1v[0], c1v[1]);
      unsigned* sb = SUBWu + (long)(s & 3) * 49152;
      ustore(sb + fdw_h, pkh);
      ustore(sb + fdw_c, pkc);
      ustore(H1Su + (long)((s + 1) & 1) * 24576 + fdw_h, push ? pkh : 0u);
      cst[0] = push ? c1v[0] : 0.f;
      cst[1] = push ? c1v[1] : 0.f;
      arrive_flag(flagS + nt * FPAD);
    }
  } else {
    // ---- word chain ----
    float cw0[2], cw1[2];
    #pragma unroll
    for (int u = 0; u < 2; ++u) { cw0[u] = clsW[j0 + u]; cw1[u] = clsW[2304 + j0 + u]; }
    for (int s = 0; s < NT - 1; ++s) {
      wait2(flagW, s, nullptr, 0);        // self-chain: usually already set
      f32x4 acc0 = {0.f, 0.f, 0.f, 0.f};
      f32x4 acc1 = {0.f, 0.f, 0.f, 0.f};
      // h2-self part (depends only on flagW)
      mfma_frag<24>((const char*)(H2Su + (long)(s & 1) * 24576),
                    l, w, w0, w1, xr0, xr1, kk, 48, acc0, acc1);
      wait2(flagS, s + 1, nullptr, 0);    // subword step s published
      // subword-output part
      mfma_frag<48>((const char*)(SUBWu + (long)(s & 3) * 49152),
                    l, w, w0, w1, xr0, xr1, kk, 0, acc0, acc1);
      #pragma unroll
      for (int r = 0; r < 4; ++r) {
        gl[16 * w + 4 * lh + r][lr]      = acc0[r];
        gl[16 * w + 4 * lh + r][16 + lr] = acc1[r];
      }
      __syncthreads();
      float p0 = 0.f, p1 = 0.f;
      float h2v[2], c2v[2];
      #pragma unroll
      for (int u = 0; u < 2; ++u) {
        int col = 4 * (jj + u);
        float vi = gl[b][col + 0] + bv[u][0];
        float vf = gl[b][col + 1] + bv[u][1];
        float vg = gl[b][col + 2] + bv[u][2];
        float vo = gl[b][col + 3] + bv[u][3];
        float si = fast_sig(vi), sf = fast_sig(vf), so = fast_sig(vo);
        float tg = fast_tanh(vg);
        c2v[u] = sf * cst[u] + si * tg;
        h2v[u] = so * fast_tanh(c2v[u]);
        p0 += h2v[u] * cw0[u];
        p1 += h2v[u] * cw1[u];
      }
      int g = gp[s];
      bool push = (g >= 1);
      #pragma unroll
      for (int u = 0; u < 2; ++u) {
        cst[u]  = push ? c2v[u] : cst[u];
        hreg[u] = push ? h2v[u] : hreg[u];
      }
      ustore(H2Su + (long)((s + 1) & 1) * 24576 + fdw_h, pack2(hreg[0], hreg[1]));
      p0 += __shfl_down(p0, 1); p1 += __shfl_down(p1, 1);
      p0 += __shfl_down(p0, 2); p1 += __shfl_down(p1, 2);
      if ((tid & 3) == 0) {
        int bb = tid >> 2;
        atomicAdd(&out[((long)bb * NT + s + 1) * 2 + 0], p0);
        atomicAdd(&out[((long)bb * NT + s + 1) * 2 + 1], p1);
      }
      if (s < NT - 2) arrive_flag(flagW + nt * FPAD);
    }
  }
}

// ---------------------------------------------------------------------------
// Host launcher
// ---------------------------------------------------------------------------
extern "C" void kernel_launch(void* const* d_in, const int* in_sizes, int n_in,
                              void* d_out, int out_size, void* d_ws, size_t ws_size,
                              hipStream_t stream)
{
  const float* x     = (const float*)d_in[0];
  const int*   golds = (const int*)d_in[1];
  const float* WihF  = (const float*)d_in[2];
  const float* WhhF  = (const float*)d_in[3];
  const float* bF    = (const float*)d_in[4];
  const float* WihB  = (const float*)d_in[5];
  const float* WhhB  = (const float*)d_in[6];
  const float* bB    = (const float*)d_in[7];
  const float* WihS  = (const float*)d_in[8];
  const float* WhhS  = (const float*)d_in[9];
  const float* bS    = (const float*)d_in[10];
  const float* WihW  = (const float*)d_in[11];
  const float* WhhW  = (const float*)d_in[12];
  const float* bW    = (const float*)d_in[13];
  const float* clsW  = (const float*)d_in[14];
  const float* clsb  = (const float*)d_in[15];
  float* out = (float*)d_out;

  // workspace layout (bytes)
  const size_t OFF_X16  = 0;                   // 25165824
  const size_t OFF_WF   = 25165824;            //  9437184
  const size_t OFF_WB   = 34603008;            //  9437184
  const size_t OFF_WS   = 44040192;            // 14155776
  const size_t OFF_WW   = 58195968;            // 14155776
  const size_t OFF_L16  = 72351744;            // 50331648
  const size_t OFF_H16  = 122683392;           //   393216 (frag [2][2])
  const size_t OFF_H1S  = 123076608;           //   196608 (frag [2])
  const size_t OFF_H2S  = 123273216;           //   196608 (frag [2])
  const size_t OFF_SUBW = 123469824;           //   786432 (frag ring [4])
  const size_t OFF_FLG  = 124256256;           //    49152 (4*96*128B)
  const size_t WS_NEEDED = 124305408;

  if (ws_size < WS_NEEDED) {
    fill_sentinel<<<(out_size + 255) / 256, 256, 0, stream>>>(out, out_size, 12345.f);
    return;
  }

  char* ws = (char*)d_ws;
  __hip_bfloat16* X16  = (__hip_bfloat16*)(ws + OFF_X16);
  __hip_bfloat16* WF   = (__hip_bfloat16*)(ws + OFF_WF);
  __hip_bfloat16* WB   = (__hip_bfloat16*)(ws + OFF_WB);
  __hip_bfloat16* WSp  = (__hip_bfloat16*)(ws + OFF_WS);
  __hip_bfloat16* WWp  = (__hip_bfloat16*)(ws + OFF_WW);
  __hip_bfloat16* L16  = (__hip_bfloat16*)(ws + OFF_L16);
  unsigned*       H16u = (unsigned*)(ws + OFF_H16);
  unsigned*       H1Su = (unsigned*)(ws + OFF_H1S);
  unsigned*       H2Su = (unsigned*)(ws + OFF_H2S);
  unsigned*       SUBWu= (unsigned*)(ws + OFF_SUBW);
  int*            flags= (int*)(ws + OFF_FLG);

  // fused setup: cvt x + pack all 4 weight matrices (one launch)
  setup_kernel<<<4096, 256, 0, stream>>>(x, WihF, WhhF, WihB, WhhB,
                                         WihS, WhhS, WihW, WhhW,
                                         X16, WF, WB, WSp, WWp);
  hipMemsetAsync(ws + OFF_H16, 0, WS_NEEDED - OFF_H16, stream);

  // phase 1: persistent BiLSTM (256 internal flag-sync steps)
  bilstm_persist<<<192, 256, 0, stream>>>(X16, WF, WB, bF, bB, H16u, L16, flags);

  // cls x-part + pred0 (full overwrite of out)
  clsx_kernel<<<NT, 256, 0, stream>>>(L16, clsW, clsb, out);

  // phase 2: persistent stack-LSTM, subword/word chains pipelined
  stack_persist<<<192, 256, 0, stream>>>(L16, WSp, WWp, bS, bW, golds, clsW,
                                         H1Su, H2Su, SUBWu, out, flags);
}